// Round 1
// baseline (792.016 us; speedup 1.0000x reference)
//
#include <hip/hip_runtime.h>

#define B 16
#define T 128
#define D 256
#define H 64
#define C1 64
#define C2 20
#define K2 4096   // H*C1
#define F2 1280   // H*C2
#define OUTW 32
#define ALPHA 0.2f

// ---------------------------------------------------------------------------
// Kernel 1: Wh1[b,h,t,c] = sum_d x[b,t,d]*W1[h,d,c] + b1[h,c]
//           src1[b,h,t] = <Wh1[b,h,t,:], a1s[h,:]>, dst1 likewise.
// grid = B*H blocks, 256 threads. LDS-chunked K (KC=64), 8t x 4c reg tile.
// ---------------------------------------------------------------------------
__global__ __launch_bounds__(256) void wh1_kernel(
    const float* __restrict__ x, const float* __restrict__ W1,
    const float* __restrict__ b1, const float* __restrict__ a1s,
    const float* __restrict__ a1d,
    float* __restrict__ wh1, float* __restrict__ src1, float* __restrict__ dst1)
{
    int blk = blockIdx.x; int b = blk >> 6, h = blk & 63;
    __shared__ float xs[128][65];            // pad 65: conflict-free column reads
    __shared__ alignas(16) float w1s[64][68]; // pad 68: 16B-aligned rows for float4
    int tid = threadIdx.x;
    int tx = tid & 15, ty = tid >> 4;        // tx: c-quad, ty: row group of 8
    float acc[8][4] = {};

    for (int kc = 0; kc < 4; ++kc) {
        int k0 = kc * 64;
        __syncthreads();
        // stage x[b, :, k0:k0+64] -> xs (coalesced)
        for (int e = 0; e < 32; ++e) {
            int idx = e * 256 + tid; int t = idx >> 6, dd = idx & 63;
            xs[t][dd] = x[(size_t)b * T * D + (size_t)t * D + k0 + dd];
        }
        // stage W1[h, k0:k0+64, :] -> w1s (coalesced)
        for (int e = 0; e < 16; ++e) {
            int idx = e * 256 + tid; int dr = idx >> 6, c = idx & 63;
            w1s[dr][c] = W1[(size_t)h * D * C1 + (size_t)(k0 + dr) * C1 + c];
        }
        __syncthreads();
        for (int dcol = 0; dcol < 64; ++dcol) {
            float4 wv = *(const float4*)&w1s[dcol][tx * 4];
            #pragma unroll
            for (int i = 0; i < 8; ++i) {
                float xv = xs[ty * 8 + i][dcol];
                acc[i][0] = fmaf(xv, wv.x, acc[i][0]);
                acc[i][1] = fmaf(xv, wv.y, acc[i][1]);
                acc[i][2] = fmaf(xv, wv.z, acc[i][2]);
                acc[i][3] = fmaf(xv, wv.w, acc[i][3]);
            }
        }
    }

    float4 bv  = *(const float4*)&b1 [h * C1 + tx * 4];
    float4 asv = *(const float4*)&a1s[h * C1 + tx * 4];
    float4 adv = *(const float4*)&a1d[h * C1 + tx * 4];
    #pragma unroll
    for (int i = 0; i < 8; ++i) {
        int t = ty * 8 + i;
        float4 v;
        v.x = acc[i][0] + bv.x; v.y = acc[i][1] + bv.y;
        v.z = acc[i][2] + bv.z; v.w = acc[i][3] + bv.w;
        *(float4*)&wh1[((size_t)blk * T + t) * C1 + tx * 4] = v;
        float s  = v.x * asv.x + v.y * asv.y + v.z * asv.z + v.w * asv.w;
        float ds = v.x * adv.x + v.y * adv.y + v.z * adv.z + v.w * adv.w;
        s  += __shfl_xor(s, 1);  s  += __shfl_xor(s, 2);
        s  += __shfl_xor(s, 4);  s  += __shfl_xor(s, 8);
        ds += __shfl_xor(ds, 1); ds += __shfl_xor(ds, 2);
        ds += __shfl_xor(ds, 4); ds += __shfl_xor(ds, 8);
        if (tx == 0) { src1[blk * T + t] = s; dst1[blk * T + t] = ds; }
    }
}

// ---------------------------------------------------------------------------
// Kernel 2: attention-1. Per (b,h): e_ij = leaky(src_i + dst_j + a1b),
// softmax over j, out[i,c] = sigmoid(relu(sum_j p_ij * Wh1[j,c])).
// Writes c1[b, i, h*64+c].
// ---------------------------------------------------------------------------
__global__ __launch_bounds__(256) void attn1_kernel(
    const float* __restrict__ wh1, const float* __restrict__ src1,
    const float* __restrict__ dst1, const float* __restrict__ a1b,
    float* __restrict__ c1)
{
    int blk = blockIdx.x; int b = blk >> 6, h = blk & 63;
    __shared__ float whs[128][65];
    __shared__ alignas(16) float pT[4][128][4];
    __shared__ float ss[128], ddv[128];
    int tid = threadIdx.x; int w = tid >> 6, lane = tid & 63;
    const float ab = a1b[h];
    const size_t base = (size_t)blk * (T * C1);

    for (int e = 0; e < 32; ++e) {
        int idx = e * 256 + tid; int t = idx >> 6, c = idx & 63;
        whs[t][c] = wh1[base + idx];
    }
    if (tid < 128) { ss[tid] = src1[blk * T + tid]; ddv[tid] = dst1[blk * T + tid]; }
    __syncthreads();

    float dj0 = ddv[lane], dj1 = ddv[lane + 64];
    for (int q = 0; q < 8; ++q) {
        for (int r = 0; r < 4; ++r) {
            int i = w * 32 + q * 4 + r;
            float si = ss[i];
            float e0 = si + dj0 + ab; e0 = e0 >= 0.f ? e0 : ALPHA * e0;
            float e1 = si + dj1 + ab; e1 = e1 >= 0.f ? e1 : ALPHA * e1;
            float m = fmaxf(e0, e1);
            for (int msk = 1; msk < 64; msk <<= 1) m = fmaxf(m, __shfl_xor(m, msk));
            float p0 = __expf(e0 - m), p1 = __expf(e1 - m);
            float sum = p0 + p1;
            for (int msk = 1; msk < 64; msk <<= 1) sum += __shfl_xor(sum, msk);
            float inv = 1.0f / sum;
            pT[w][lane][r] = p0 * inv; pT[w][lane + 64][r] = p1 * inv;
        }
        float a0 = 0, a1 = 0, a2 = 0, a3 = 0;
        for (int j = 0; j < 128; ++j) {
            float4 pv = *(const float4*)&pT[w][j][0];  // wave-broadcast
            float wj = whs[j][lane];
            a0 = fmaf(pv.x, wj, a0); a1 = fmaf(pv.y, wj, a1);
            a2 = fmaf(pv.z, wj, a2); a3 = fmaf(pv.w, wj, a3);
        }
        int i0 = w * 32 + q * 4;
        float vals[4] = {a0, a1, a2, a3};
        #pragma unroll
        for (int r = 0; r < 4; ++r) {
            float v = vals[r]; v = v > 0.f ? v : 0.f;
            v = 1.0f / (1.0f + __expf(-v));
            c1[((size_t)b * T + i0 + r) * K2 + h * C1 + lane] = v;
        }
    }
}

// ---------------------------------------------------------------------------
// Kernel 3: Wh2[b,h,t,c] = sum_k c1[b,t,k]*W2[h,k,c] + b2[h,c]  (K=4096!)
// plus src2/dst2. grid = B * (H/2) blocks (2 heads share staged c1 chunk).
// 4t x 5c register tile, float4 LDS reads over k.
// ---------------------------------------------------------------------------
__global__ __launch_bounds__(256) void wh2_kernel(
    const float* __restrict__ c1, const float* __restrict__ W2,
    const float* __restrict__ b2, const float* __restrict__ a2s,
    const float* __restrict__ a2d,
    float* __restrict__ wh2, float* __restrict__ src2, float* __restrict__ dst2)
{
    int blk = blockIdx.x; int b = blk >> 5, hp = blk & 31; int h0 = hp * 2;
    __shared__ alignas(16) float c1s[128][68];
    __shared__ alignas(16) float w2sT[2][20][68];   // transposed [c][k]
    int tid = threadIdx.x;
    int cgq = tid & 3, tg = (tid >> 2) & 31, hl = tid >> 7;
    int c0 = cgq * 5, h = h0 + hl;
    float acc[4][5] = {};

    for (int kc = 0; kc < 64; ++kc) {
        int k0 = kc * 64;
        __syncthreads();
        // stage c1[b, :, k0:k0+64] as float4
        for (int e = 0; e < 8; ++e) {
            int i4 = e * 256 + tid;            // 0..2047
            int t = i4 >> 4, c4 = i4 & 15;
            float4 v = *(const float4*)&c1[((size_t)b * T + t) * K2 + k0 + c4 * 4];
            *(float4*)&c1s[t][c4 * 4] = v;
        }
        // stage W2[h0..h0+1, k0:k0+64, :] transposed to [c][k]
        for (int e = 0; e < 3; ++e) {
            int i4 = e * 256 + tid;            // 0..639 (2 heads * 320 float4)
            if (i4 < 640) {
                int hl2 = i4 >= 320 ? 1 : 0; int rem = i4 - hl2 * 320;
                float4 v = *(const float4*)&W2[(size_t)(h0 + hl2) * K2 * C2
                                               + (size_t)k0 * C2 + rem * 4];
                float vv[4] = {v.x, v.y, v.z, v.w};
                #pragma unroll
                for (int j = 0; j < 4; ++j) {
                    int ff = rem * 4 + j;
                    int dloc = ff / 20, cloc = ff - dloc * 20;
                    w2sT[hl2][cloc][dloc] = vv[j];
                }
            }
        }
        __syncthreads();
        for (int dq = 0; dq < 16; ++dq) {
            int d4 = dq * 4;
            float4 xv[4], wv[5];
            #pragma unroll
            for (int i = 0; i < 4; ++i) xv[i] = *(const float4*)&c1s[tg + 32 * i][d4];
            #pragma unroll
            for (int c = 0; c < 5; ++c) wv[c] = *(const float4*)&w2sT[hl][c0 + c][d4];
            #pragma unroll
            for (int i = 0; i < 4; ++i)
                #pragma unroll
                for (int c = 0; c < 5; ++c)
                    acc[i][c] += xv[i].x * wv[c].x + xv[i].y * wv[c].y
                               + xv[i].z * wv[c].z + xv[i].w * wv[c].w;
        }
    }

    float bvv[5], asv[5], adv[5];
    #pragma unroll
    for (int c = 0; c < 5; ++c) {
        bvv[c] = b2 [h * C2 + c0 + c];
        asv[c] = a2s[h * C2 + c0 + c];
        adv[c] = a2d[h * C2 + c0 + c];
    }
    #pragma unroll
    for (int i = 0; i < 4; ++i) {
        int t = tg + 32 * i;
        float s = 0, ds = 0;
        #pragma unroll
        for (int c = 0; c < 5; ++c) {
            float v = acc[i][c] + bvv[c];
            wh2[((size_t)(b * H + h) * T + t) * C2 + c0 + c] = v;
            s  = fmaf(v, asv[c], s);
            ds = fmaf(v, adv[c], ds);
        }
        s  += __shfl_xor(s, 1);  s  += __shfl_xor(s, 2);
        ds += __shfl_xor(ds, 1); ds += __shfl_xor(ds, 2);
        if (cgq == 0) { src2[(b * H + h) * T + t] = s; dst2[(b * H + h) * T + t] = ds; }
    }
}

// ---------------------------------------------------------------------------
// Kernel 4: attention-2 (C2=20). Writes c2[b, i, h*20+c].
// ---------------------------------------------------------------------------
__global__ __launch_bounds__(256) void attn2_kernel(
    const float* __restrict__ wh2, const float* __restrict__ src2,
    const float* __restrict__ dst2, const float* __restrict__ a2b,
    float* __restrict__ c2)
{
    int blk = blockIdx.x; int b = blk >> 6, h = blk & 63;
    __shared__ float whs[128][32];          // cols 20..31 zero-padded
    __shared__ alignas(16) float pT[4][128][4];
    __shared__ float ss[128], ddv[128];
    int tid = threadIdx.x; int w = tid >> 6, lane = tid & 63;
    const float ab = a2b[h];
    const size_t base = (size_t)blk * (T * C2);

    for (int e = 0; e < 10; ++e) {
        int idx = e * 256 + tid;            // 0..2559
        int t = idx / 20, c = idx - t * 20;
        whs[t][c] = wh2[base + idx];
    }
    for (int e = 0; e < 6; ++e) {
        int idx = e * 256 + tid;
        if (idx < 1536) { int t = idx / 12, c = 20 + (idx - t * 12); whs[t][c] = 0.f; }
    }
    if (tid < 128) { ss[tid] = src2[blk * T + tid]; ddv[tid] = dst2[blk * T + tid]; }
    __syncthreads();

    float dj0 = ddv[lane], dj1 = ddv[lane + 64];
    int cc = lane & 31, jh = lane >> 5;
    for (int q = 0; q < 8; ++q) {
        for (int r = 0; r < 4; ++r) {
            int i = w * 32 + q * 4 + r;
            float si = ss[i];
            float e0 = si + dj0 + ab; e0 = e0 >= 0.f ? e0 : ALPHA * e0;
            float e1 = si + dj1 + ab; e1 = e1 >= 0.f ? e1 : ALPHA * e1;
            float m = fmaxf(e0, e1);
            for (int msk = 1; msk < 64; msk <<= 1) m = fmaxf(m, __shfl_xor(m, msk));
            float p0 = __expf(e0 - m), p1 = __expf(e1 - m);
            float sum = p0 + p1;
            for (int msk = 1; msk < 64; msk <<= 1) sum += __shfl_xor(sum, msk);
            float inv = 1.0f / sum;
            pT[w][lane][r] = p0 * inv; pT[w][lane + 64][r] = p1 * inv;
        }
        float a0 = 0, a1 = 0, a2 = 0, a3 = 0;
        for (int jj = 0; jj < 64; ++jj) {
            int j = jh * 64 + jj;
            float4 pv = *(const float4*)&pT[w][j][0];
            float wj = whs[j][cc];          // zero for cc >= 20
            a0 = fmaf(pv.x, wj, a0); a1 = fmaf(pv.y, wj, a1);
            a2 = fmaf(pv.z, wj, a2); a3 = fmaf(pv.w, wj, a3);
        }
        a0 += __shfl_xor(a0, 32); a1 += __shfl_xor(a1, 32);
        a2 += __shfl_xor(a2, 32); a3 += __shfl_xor(a3, 32);
        if (jh == 0 && cc < 20) {
            int i0 = w * 32 + q * 4;
            float vals[4] = {a0, a1, a2, a3};
            #pragma unroll
            for (int r = 0; r < 4; ++r) {
                float v = vals[r]; v = v > 0.f ? v : 0.f;
                v = 1.0f / (1.0f + __expf(-v));
                c2[((size_t)b * T + i0 + r) * F2 + h * C2 + cc] = v;
            }
        }
    }
}

// ---------------------------------------------------------------------------
// Kernel 5: c3 = c2 @ sl_w + sl_b   ([2048,1280]@[1280,256])
// grid = 64 row-tiles(32) x 4 col-tiles(64). 2t x 4c reg tile.
// ---------------------------------------------------------------------------
__global__ __launch_bounds__(256) void sl_kernel(
    const float* __restrict__ c2, const float* __restrict__ slw,
    const float* __restrict__ slb, float* __restrict__ c3)
{
    int rt = blockIdx.x >> 2; int ct = (blockIdx.x & 3) * 64;
    __shared__ float xs[32][65];
    __shared__ alignas(16) float ws[64][68];
    int tid = threadIdx.x;
    int cgi = tid & 15, tq = tid >> 4;
    float acc[2][4] = {};

    for (int kc = 0; kc < 20; ++kc) {
        int k0 = kc * 64;
        __syncthreads();
        for (int e = 0; e < 8; ++e) {
            int idx = e * 256 + tid; int r = idx >> 6, dcol = idx & 63;
            xs[r][dcol] = c2[(size_t)(rt * 32 + r) * F2 + k0 + dcol];
        }
        for (int e = 0; e < 16; ++e) {
            int idx = e * 256 + tid; int dr = idx >> 6, ccol = idx & 63;
            ws[dr][ccol] = slw[(size_t)(k0 + dr) * D + ct + ccol];
        }
        __syncthreads();
        for (int dcol = 0; dcol < 64; ++dcol) {
            float4 wv = *(const float4*)&ws[dcol][cgi * 4];
            float x0 = xs[tq * 2][dcol], x1 = xs[tq * 2 + 1][dcol];
            acc[0][0] = fmaf(x0, wv.x, acc[0][0]); acc[0][1] = fmaf(x0, wv.y, acc[0][1]);
            acc[0][2] = fmaf(x0, wv.z, acc[0][2]); acc[0][3] = fmaf(x0, wv.w, acc[0][3]);
            acc[1][0] = fmaf(x1, wv.x, acc[1][0]); acc[1][1] = fmaf(x1, wv.y, acc[1][1]);
            acc[1][2] = fmaf(x1, wv.z, acc[1][2]); acc[1][3] = fmaf(x1, wv.w, acc[1][3]);
        }
    }
    float4 bv = *(const float4*)&slb[ct + cgi * 4];
    #pragma unroll
    for (int i = 0; i < 2; ++i) {
        float4 v;
        v.x = acc[i][0] + bv.x; v.y = acc[i][1] + bv.y;
        v.z = acc[i][2] + bv.z; v.w = acc[i][3] + bv.w;
        *(float4*)&c3[(size_t)(rt * 32 + tq * 2 + i) * D + ct + cgi * 4] = v;
    }
}

// ---------------------------------------------------------------------------
// Kernel 6: res[b,o,d] = sum_t c3[b,t,d]*gar_w[t,o] + gar_b[o]
// ---------------------------------------------------------------------------
__global__ __launch_bounds__(256) void gar_kernel(
    const float* __restrict__ c3, const float* __restrict__ garw,
    const float* __restrict__ garb, float* __restrict__ out)
{
    int blk = blockIdx.x; int b = blk >> 5, o = blk & 31;
    int dcol = threadIdx.x;
    float acc = garb[o];
    const float* cp = c3 + (size_t)b * T * D + dcol;
    for (int t = 0; t < T; ++t)
        acc = fmaf(cp[(size_t)t * D], garw[t * OUTW + o], acc);
    out[((size_t)b * OUTW + o) * D + dcol] = acc;
}

// ---------------------------------------------------------------------------
extern "C" void kernel_launch(void* const* d_in, const int* in_sizes, int n_in,
                              void* d_out, int out_size, void* d_ws, size_t ws_size,
                              hipStream_t stream) {
    const float* x    = (const float*)d_in[0];
    const float* W1   = (const float*)d_in[1];
    const float* b1   = (const float*)d_in[2];
    const float* a1s  = (const float*)d_in[3];
    const float* a1d  = (const float*)d_in[4];
    const float* a1b  = (const float*)d_in[5];
    const float* W2   = (const float*)d_in[6];
    const float* b2   = (const float*)d_in[7];
    const float* a2s  = (const float*)d_in[8];
    const float* a2d  = (const float*)d_in[9];
    const float* a2b  = (const float*)d_in[10];
    const float* slw  = (const float*)d_in[11];
    const float* slb  = (const float*)d_in[12];
    const float* garw = (const float*)d_in[13];
    const float* garb = (const float*)d_in[14];

    float* wsf  = (float*)d_ws;
    float* wh1  = wsf;                 // B*H*T*C1 = 8388608
    float* src1 = wh1  + 8388608;      // 131072
    float* dst1 = src1 + 131072;       // 131072
    float* c1   = dst1 + 131072;       // B*T*K2 = 8388608
    float* wh2  = c1   + 8388608;      // B*H*T*C2 = 2621440
    float* src2 = wh2  + 2621440;      // 131072
    float* dst2 = src2 + 131072;       // 131072
    float* c2   = dst2 + 131072;       // B*T*F2 = 2621440
    float* c3   = c2   + 2621440;      // B*T*D = 524288
    // total = 23,068,672 floats = 92.3 MB of d_ws

    wh1_kernel  <<<B * H,      256, 0, stream>>>(x, W1, b1, a1s, a1d, wh1, src1, dst1);
    attn1_kernel<<<B * H,      256, 0, stream>>>(wh1, src1, dst1, a1b, c1);
    wh2_kernel  <<<B * (H / 2), 256, 0, stream>>>(c1, W2, b2, a2s, a2d, wh2, src2, dst2);
    attn2_kernel<<<B * H,      256, 0, stream>>>(wh2, src2, dst2, a2b, c2);
    sl_kernel   <<<64 * 4,     256, 0, stream>>>(c2, slw, slb, c3);
    gar_kernel  <<<B * OUTW,   256, 0, stream>>>(c3, garw, garb, (float*)d_out);
}

// Round 2
// 526.441 us; speedup vs baseline: 1.5045x; 1.5045x over previous
//
#include <hip/hip_runtime.h>
#include <hip/hip_bf16.h>

#define B 16
#define T 128
#define D 256
#define H 64
#define C1 64
#define C2 20
#define K2 4096   // H*C1
#define F2 1280   // H*C2
#define OUTW 32
#define ALPHA 0.2f

typedef __attribute__((ext_vector_type(8))) short short8;
typedef __attribute__((ext_vector_type(4))) float f32x4;

// ---------------------------------------------------------------------------
// Kernel 1: Wh1[b,h,t,c] = sum_d x[b,t,d]*W1[h,d,c] + b1[h,c]
//           src1[b,h,t] = <Wh1[b,h,t,:], a1s[h,:]>, dst1 likewise.
// ---------------------------------------------------------------------------
__global__ __launch_bounds__(256) void wh1_kernel(
    const float* __restrict__ x, const float* __restrict__ W1,
    const float* __restrict__ b1, const float* __restrict__ a1s,
    const float* __restrict__ a1d,
    float* __restrict__ wh1, float* __restrict__ src1, float* __restrict__ dst1)
{
    int blk = blockIdx.x; int b = blk >> 6, h = blk & 63;
    __shared__ float xs[128][65];
    __shared__ alignas(16) float w1s[64][68];
    int tid = threadIdx.x;
    int tx = tid & 15, ty = tid >> 4;
    float acc[8][4] = {};

    for (int kc = 0; kc < 4; ++kc) {
        int k0 = kc * 64;
        __syncthreads();
        for (int e = 0; e < 32; ++e) {
            int idx = e * 256 + tid; int t = idx >> 6, dd = idx & 63;
            xs[t][dd] = x[(size_t)b * T * D + (size_t)t * D + k0 + dd];
        }
        for (int e = 0; e < 16; ++e) {
            int idx = e * 256 + tid; int dr = idx >> 6, c = idx & 63;
            w1s[dr][c] = W1[(size_t)h * D * C1 + (size_t)(k0 + dr) * C1 + c];
        }
        __syncthreads();
        for (int dcol = 0; dcol < 64; ++dcol) {
            float4 wv = *(const float4*)&w1s[dcol][tx * 4];
            #pragma unroll
            for (int i = 0; i < 8; ++i) {
                float xv = xs[ty * 8 + i][dcol];
                acc[i][0] = fmaf(xv, wv.x, acc[i][0]);
                acc[i][1] = fmaf(xv, wv.y, acc[i][1]);
                acc[i][2] = fmaf(xv, wv.z, acc[i][2]);
                acc[i][3] = fmaf(xv, wv.w, acc[i][3]);
            }
        }
    }

    float4 bv  = *(const float4*)&b1 [h * C1 + tx * 4];
    float4 asv = *(const float4*)&a1s[h * C1 + tx * 4];
    float4 adv = *(const float4*)&a1d[h * C1 + tx * 4];
    #pragma unroll
    for (int i = 0; i < 8; ++i) {
        int t = ty * 8 + i;
        float4 v;
        v.x = acc[i][0] + bv.x; v.y = acc[i][1] + bv.y;
        v.z = acc[i][2] + bv.z; v.w = acc[i][3] + bv.w;
        *(float4*)&wh1[((size_t)blk * T + t) * C1 + tx * 4] = v;
        float s  = v.x * asv.x + v.y * asv.y + v.z * asv.z + v.w * asv.w;
        float ds = v.x * adv.x + v.y * adv.y + v.z * adv.z + v.w * adv.w;
        s  += __shfl_xor(s, 1);  s  += __shfl_xor(s, 2);
        s  += __shfl_xor(s, 4);  s  += __shfl_xor(s, 8);
        ds += __shfl_xor(ds, 1); ds += __shfl_xor(ds, 2);
        ds += __shfl_xor(ds, 4); ds += __shfl_xor(ds, 8);
        if (tx == 0) { src1[blk * T + t] = s; dst1[blk * T + t] = ds; }
    }
}

// ---------------------------------------------------------------------------
// Kernel 2: attention-1. Writes c1 as BF16 in [b, t, h*64+c] layout.
// ---------------------------------------------------------------------------
__global__ __launch_bounds__(256) void attn1_kernel(
    const float* __restrict__ wh1, const float* __restrict__ src1,
    const float* __restrict__ dst1, const float* __restrict__ a1b,
    __hip_bfloat16* __restrict__ c1)
{
    int blk = blockIdx.x; int b = blk >> 6, h = blk & 63;
    __shared__ float whs[128][65];
    __shared__ alignas(16) float pT[4][128][4];
    __shared__ float ss[128], ddv[128];
    int tid = threadIdx.x; int w = tid >> 6, lane = tid & 63;
    const float ab = a1b[h];
    const size_t base = (size_t)blk * (T * C1);

    for (int e = 0; e < 32; ++e) {
        int idx = e * 256 + tid; int t = idx >> 6, c = idx & 63;
        whs[t][c] = wh1[base + idx];
    }
    if (tid < 128) { ss[tid] = src1[blk * T + tid]; ddv[tid] = dst1[blk * T + tid]; }
    __syncthreads();

    float dj0 = ddv[lane], dj1 = ddv[lane + 64];
    for (int q = 0; q < 8; ++q) {
        for (int r = 0; r < 4; ++r) {
            int i = w * 32 + q * 4 + r;
            float si = ss[i];
            float e0 = si + dj0 + ab; e0 = e0 >= 0.f ? e0 : ALPHA * e0;
            float e1 = si + dj1 + ab; e1 = e1 >= 0.f ? e1 : ALPHA * e1;
            float m = fmaxf(e0, e1);
            for (int msk = 1; msk < 64; msk <<= 1) m = fmaxf(m, __shfl_xor(m, msk));
            float p0 = __expf(e0 - m), p1 = __expf(e1 - m);
            float sum = p0 + p1;
            for (int msk = 1; msk < 64; msk <<= 1) sum += __shfl_xor(sum, msk);
            float inv = 1.0f / sum;
            pT[w][lane][r] = p0 * inv; pT[w][lane + 64][r] = p1 * inv;
        }
        float a0 = 0, a1 = 0, a2 = 0, a3 = 0;
        for (int j = 0; j < 128; ++j) {
            float4 pv = *(const float4*)&pT[w][j][0];
            float wj = whs[j][lane];
            a0 = fmaf(pv.x, wj, a0); a1 = fmaf(pv.y, wj, a1);
            a2 = fmaf(pv.z, wj, a2); a3 = fmaf(pv.w, wj, a3);
        }
        int i0 = w * 32 + q * 4;
        float vals[4] = {a0, a1, a2, a3};
        #pragma unroll
        for (int r = 0; r < 4; ++r) {
            float v = vals[r]; v = v > 0.f ? v : 0.f;
            v = 1.0f / (1.0f + __expf(-v));
            c1[((size_t)b * T + i0 + r) * K2 + h * C1 + lane] = __float2bfloat16(v);
        }
    }
}

// ---------------------------------------------------------------------------
// Kernel 2b: W2[h,k,c] fp32 -> w2t[n=h*20+c][k] bf16  (K-contiguous B operand)
// grid = 64 heads x 32 k-blocks(128)
// ---------------------------------------------------------------------------
__global__ __launch_bounds__(256) void w2t_kernel(
    const float* __restrict__ W2, __hip_bfloat16* __restrict__ w2t)
{
    int blk = blockIdx.x; int h = blk >> 5, kb = blk & 31; int k0 = kb * 128;
    __shared__ float lw[128][21];
    int tid = threadIdx.x;
    const float* src = W2 + ((size_t)h * K2 + k0) * C2;
    for (int e = 0; e < 10; ++e) {
        int idx = e * 256 + tid; int k = idx / 20, c = idx - k * 20;
        lw[k][c] = src[idx];
    }
    __syncthreads();
    for (int e = 0; e < 10; ++e) {
        int idx = e * 256 + tid; int c = idx >> 7, k = idx & 127;
        w2t[((size_t)(h * 20 + c)) * K2 + k0 + k] = __float2bfloat16(lw[k][c]);
    }
}

// ---------------------------------------------------------------------------
// Kernel 3: MFMA GEMM  wh2m[m][n] = sum_k c1bf[m][k] * w2t[n][k] + b2f[n]
// M=2048, N=1280, K=4096. 128x128 tile, BK=64, 4 waves (2x2), 16x16x32 bf16.
// LDS pad to 72 shorts/row: staging writes and frag reads both land at the
// optimal 8 dwords/bank for b128 ops (no swizzle needed).
// ---------------------------------------------------------------------------
__global__ __launch_bounds__(256) void wh2_mfma_kernel(
    const ushort* __restrict__ Ag,   // [2048][4096] bf16 bits
    const ushort* __restrict__ Bg,   // [1280][4096] bf16 bits
    const float* __restrict__ b2f,   // [1280]
    float* __restrict__ Cm)          // [2048][1280]
{
    __shared__ ushort As[128][72];
    __shared__ ushort Bs[128][72];
    int tid = threadIdx.x;
    int bm = (blockIdx.x / 10) * 128, bn = (blockIdx.x % 10) * 128;
    int wave = tid >> 6, lane = tid & 63;
    int wm = (wave >> 1) * 64, wn = (wave & 1) * 64;
    int lr = lane & 15, lk = lane >> 4;
    int sr = tid >> 3, sc = (tid & 7) * 8;   // staging: 32 rows x 64k per pass

    f32x4 acc[4][4];
    #pragma unroll
    for (int i = 0; i < 4; ++i)
        #pragma unroll
        for (int j = 0; j < 4; ++j) acc[i][j] = (f32x4){0.f, 0.f, 0.f, 0.f};

    const ushort* Ap = Ag + (size_t)(bm + sr) * 4096 + sc;
    const ushort* Bp = Bg + (size_t)(bn + sr) * 4096 + sc;

    uint4 ra[4], rb[4];
    #pragma unroll
    for (int e = 0; e < 4; ++e) {
        ra[e] = *(const uint4*)(Ap + (size_t)e * 32 * 4096);
        rb[e] = *(const uint4*)(Bp + (size_t)e * 32 * 4096);
    }

    for (int k0 = 0; k0 < 4096; k0 += 64) {
        __syncthreads();               // previous tile's reads done
        #pragma unroll
        for (int e = 0; e < 4; ++e) {
            *(uint4*)&As[sr + e * 32][sc] = ra[e];
            *(uint4*)&Bs[sr + e * 32][sc] = rb[e];
        }
        __syncthreads();
        if (k0 + 64 < 4096) {          // prefetch next K-tile during compute
            #pragma unroll
            for (int e = 0; e < 4; ++e) {
                ra[e] = *(const uint4*)(Ap + (size_t)e * 32 * 4096 + k0 + 64);
                rb[e] = *(const uint4*)(Bp + (size_t)e * 32 * 4096 + k0 + 64);
            }
        }
        #pragma unroll
        for (int ks = 0; ks < 2; ++ks) {
            short8 af[4], bfr[4];
            #pragma unroll
            for (int i = 0; i < 4; ++i)
                af[i] = *(const short8*)&As[wm + i * 16 + lr][ks * 32 + lk * 8];
            #pragma unroll
            for (int j = 0; j < 4; ++j)
                bfr[j] = *(const short8*)&Bs[wn + j * 16 + lr][ks * 32 + lk * 8];
            #pragma unroll
            for (int i = 0; i < 4; ++i)
                #pragma unroll
                for (int j = 0; j < 4; ++j)
                    acc[i][j] = __builtin_amdgcn_mfma_f32_16x16x32_bf16(
                        af[i], bfr[j], acc[i][j], 0, 0, 0);
        }
    }

    #pragma unroll
    for (int i = 0; i < 4; ++i) {
        #pragma unroll
        for (int j = 0; j < 4; ++j) {
            int col = bn + wn + j * 16 + lr;
            float bv = b2f[col];
            #pragma unroll
            for (int r = 0; r < 4; ++r) {
                int row = bm + wm + i * 16 + lk * 4 + r;
                Cm[(size_t)row * F2 + col] = acc[i][j][r] + bv;
            }
        }
    }
}

// ---------------------------------------------------------------------------
// Kernel 4: attention-2. Reads wh2m[b*T+t][h*20+c]; computes scores in-kernel.
// ---------------------------------------------------------------------------
__global__ __launch_bounds__(256) void attn2_kernel(
    const float* __restrict__ wh2m, const float* __restrict__ a2s,
    const float* __restrict__ a2d, const float* __restrict__ a2b,
    float* __restrict__ c2)
{
    int blk = blockIdx.x; int b = blk >> 6, h = blk & 63;
    __shared__ float whs[128][33];          // cols 20..32 zero
    __shared__ alignas(16) float pT[4][128][4];
    __shared__ float ss[128], ddv[128];
    int tid = threadIdx.x; int w = tid >> 6, lane = tid & 63;
    const float ab = a2b[h];
    const float* src = wh2m + (size_t)b * T * F2 + h * C2;

    for (int e = 0; e < 10; ++e) {
        int idx = e * 256 + tid; int t = idx / 20, c = idx - t * 20;
        whs[t][c] = src[(size_t)t * F2 + c];
    }
    for (int e = 0; e < 7; ++e) {
        int idx = e * 256 + tid;
        if (idx < 1664) { int t = idx / 13, c = 20 + (idx - t * 13); whs[t][c] = 0.f; }
    }
    __syncthreads();
    if (tid < 128) {
        float s = ab, dv = 0.f;
        #pragma unroll
        for (int c = 0; c < 20; ++c) {
            float v = whs[tid][c];
            s  = fmaf(v, a2s[h * C2 + c], s);
            dv = fmaf(v, a2d[h * C2 + c], dv);
        }
        ss[tid] = s; ddv[tid] = dv;
    }
    __syncthreads();

    float dj0 = ddv[lane], dj1 = ddv[lane + 64];
    int cc = lane & 31, jh = lane >> 5;
    for (int q = 0; q < 8; ++q) {
        for (int r = 0; r < 4; ++r) {
            int i = w * 32 + q * 4 + r;
            float si = ss[i];
            float e0 = si + dj0; e0 = e0 >= 0.f ? e0 : ALPHA * e0;
            float e1 = si + dj1; e1 = e1 >= 0.f ? e1 : ALPHA * e1;
            float m = fmaxf(e0, e1);
            for (int msk = 1; msk < 64; msk <<= 1) m = fmaxf(m, __shfl_xor(m, msk));
            float p0 = __expf(e0 - m), p1 = __expf(e1 - m);
            float sum = p0 + p1;
            for (int msk = 1; msk < 64; msk <<= 1) sum += __shfl_xor(sum, msk);
            float inv = 1.0f / sum;
            pT[w][lane][r] = p0 * inv; pT[w][lane + 64][r] = p1 * inv;
        }
        float a0 = 0, a1 = 0, a2 = 0, a3 = 0;
        for (int jj = 0; jj < 64; ++jj) {
            int j = jh * 64 + jj;
            float4 pv = *(const float4*)&pT[w][j][0];
            float wj = whs[j][cc];
            a0 = fmaf(pv.x, wj, a0); a1 = fmaf(pv.y, wj, a1);
            a2 = fmaf(pv.z, wj, a2); a3 = fmaf(pv.w, wj, a3);
        }
        a0 += __shfl_xor(a0, 32); a1 += __shfl_xor(a1, 32);
        a2 += __shfl_xor(a2, 32); a3 += __shfl_xor(a3, 32);
        if (jh == 0 && cc < 20) {
            int i0 = w * 32 + q * 4;
            float vals[4] = {a0, a1, a2, a3};
            #pragma unroll
            for (int r = 0; r < 4; ++r) {
                float v = vals[r]; v = v > 0.f ? v : 0.f;
                v = 1.0f / (1.0f + __expf(-v));
                c2[((size_t)b * T + i0 + r) * F2 + h * C2 + cc] = v;
            }
        }
    }
}

// ---------------------------------------------------------------------------
// Kernel 5: c3 = c2 @ sl_w + sl_b   ([2048,1280]@[1280,256])
// ---------------------------------------------------------------------------
__global__ __launch_bounds__(256) void sl_kernel(
    const float* __restrict__ c2, const float* __restrict__ slw,
    const float* __restrict__ slb, float* __restrict__ c3)
{
    int rt = blockIdx.x >> 2; int ct = (blockIdx.x & 3) * 64;
    __shared__ float xs[32][65];
    __shared__ alignas(16) float ws[64][68];
    int tid = threadIdx.x;
    int cgi = tid & 15, tq = tid >> 4;
    float acc[2][4] = {};

    for (int kc = 0; kc < 20; ++kc) {
        int k0 = kc * 64;
        __syncthreads();
        for (int e = 0; e < 8; ++e) {
            int idx = e * 256 + tid; int r = idx >> 6, dcol = idx & 63;
            xs[r][dcol] = c2[(size_t)(rt * 32 + r) * F2 + k0 + dcol];
        }
        for (int e = 0; e < 16; ++e) {
            int idx = e * 256 + tid; int dr = idx >> 6, ccol = idx & 63;
            ws[dr][ccol] = slw[(size_t)(k0 + dr) * D + ct + ccol];
        }
        __syncthreads();
        for (int dcol = 0; dcol < 64; ++dcol) {
            float4 wv = *(const float4*)&ws[dcol][cgi * 4];
            float x0 = xs[tq * 2][dcol], x1 = xs[tq * 2 + 1][dcol];
            acc[0][0] = fmaf(x0, wv.x, acc[0][0]); acc[0][1] = fmaf(x0, wv.y, acc[0][1]);
            acc[0][2] = fmaf(x0, wv.z, acc[0][2]); acc[0][3] = fmaf(x0, wv.w, acc[0][3]);
            acc[1][0] = fmaf(x1, wv.x, acc[1][0]); acc[1][1] = fmaf(x1, wv.y, acc[1][1]);
            acc[1][2] = fmaf(x1, wv.z, acc[1][2]); acc[1][3] = fmaf(x1, wv.w, acc[1][3]);
        }
    }
    float4 bv = *(const float4*)&slb[ct + cgi * 4];
    #pragma unroll
    for (int i = 0; i < 2; ++i) {
        float4 v;
        v.x = acc[i][0] + bv.x; v.y = acc[i][1] + bv.y;
        v.z = acc[i][2] + bv.z; v.w = acc[i][3] + bv.w;
        *(float4*)&c3[(size_t)(rt * 32 + tq * 2 + i) * D + ct + cgi * 4] = v;
    }
}

// ---------------------------------------------------------------------------
// Kernel 6: res[b,o,d] = sum_t c3[b,t,d]*gar_w[t,o] + gar_b[o]
// ---------------------------------------------------------------------------
__global__ __launch_bounds__(256) void gar_kernel(
    const float* __restrict__ c3, const float* __restrict__ garw,
    const float* __restrict__ garb, float* __restrict__ out)
{
    int blk = blockIdx.x; int b = blk >> 5, o = blk & 31;
    int dcol = threadIdx.x;
    float acc = garb[o];
    const float* cp = c3 + (size_t)b * T * D + dcol;
    for (int t = 0; t < T; ++t)
        acc = fmaf(cp[(size_t)t * D], garw[t * OUTW + o], acc);
    out[((size_t)b * OUTW + o) * D + dcol] = acc;
}

// ---------------------------------------------------------------------------
extern "C" void kernel_launch(void* const* d_in, const int* in_sizes, int n_in,
                              void* d_out, int out_size, void* d_ws, size_t ws_size,
                              hipStream_t stream) {
    const float* x    = (const float*)d_in[0];
    const float* W1   = (const float*)d_in[1];
    const float* b1   = (const float*)d_in[2];
    const float* a1s  = (const float*)d_in[3];
    const float* a1d  = (const float*)d_in[4];
    const float* a1b  = (const float*)d_in[5];
    const float* W2   = (const float*)d_in[6];
    const float* b2   = (const float*)d_in[7];
    const float* a2s  = (const float*)d_in[8];
    const float* a2d  = (const float*)d_in[9];
    const float* a2b  = (const float*)d_in[10];
    const float* slw  = (const float*)d_in[11];
    const float* slb  = (const float*)d_in[12];
    const float* garw = (const float*)d_in[13];
    const float* garb = (const float*)d_in[14];

    float* wsf  = (float*)d_ws;
    float* wh1  = wsf;                               // 8388608 f
    float* src1 = wh1  + 8388608;                    // 131072 f
    float* dst1 = src1 + 131072;                     // 131072 f
    __hip_bfloat16* c1bf = (__hip_bfloat16*)(dst1 + 131072);   // 8388608 bf16
    __hip_bfloat16* w2t  = c1bf + 8388608;                     // 5242880 bf16
    float* wh2m = (float*)(w2t + 5242880);           // 2621440 f
    float* c2   = wh2m + 2621440;                    // 2621440 f
    float* c3   = c2   + 2621440;                    // 524288 f

    w2t_kernel     <<<2048,  256, 0, stream>>>(W2, w2t);
    wh1_kernel     <<<B * H, 256, 0, stream>>>(x, W1, b1, a1s, a1d, wh1, src1, dst1);
    attn1_kernel   <<<B * H, 256, 0, stream>>>(wh1, src1, dst1, a1b, c1bf);
    wh2_mfma_kernel<<<160,   256, 0, stream>>>((const ushort*)c1bf, (const ushort*)w2t,
                                               b2, wh2m);
    attn2_kernel   <<<B * H, 256, 0, stream>>>(wh2m, a2s, a2d, a2b, c2);
    sl_kernel      <<<256,   256, 0, stream>>>(c2, slw, slb, c3);
    gar_kernel     <<<B * OUTW, 256, 0, stream>>>(c3, garw, garb, (float*)d_out);
}

// Round 4
// 396.483 us; speedup vs baseline: 1.9976x; 1.3278x over previous
//
#include <hip/hip_runtime.h>
#include <hip/hip_bf16.h>

#define B 16
#define T 128
#define D 256
#define H 64
#define C1 64
#define C2 20
#define K2 4096   // H*C1
#define F2 1280   // H*C2
#define OUTW 32
#define ALPHA 0.2f

typedef __attribute__((ext_vector_type(8))) short short8;
typedef __attribute__((ext_vector_type(4))) float f32x4;

static __device__ __forceinline__ ushort f2bf(float f) {
    __hip_bfloat16 h = __float2bfloat16(f);
    return *reinterpret_cast<ushort*>(&h);
}

// ---------------------------------------------------------------------------
// Templated MFMA GEMM: C[m][n] = sum_k A[m][k]*Bt[n][k] + bias[n]
// A: [M][KD] bf16, Bt: [NBLK*128][KD] bf16, C: [M][NBLK*128] fp32.
// 128x128 tile, BK=64, 4 waves (2x2), 16x16x32 bf16, reg->LDS prefetch.
// (verified correct in round 2 as wh2_mfma_kernel)
// ---------------------------------------------------------------------------
template<int KD, int NBLK>
__global__ __launch_bounds__(256) void gemm_bf16_kernel(
    const ushort* __restrict__ Ag, const ushort* __restrict__ Bg,
    const float* __restrict__ bias, float* __restrict__ Cm)
{
    __shared__ ushort As[128][72];
    __shared__ ushort Bs[128][72];
    const int NN = NBLK * 128;
    int tid = threadIdx.x;
    int bm = (blockIdx.x / NBLK) * 128, bn = (blockIdx.x % NBLK) * 128;
    int wave = tid >> 6, lane = tid & 63;
    int wm = (wave >> 1) * 64, wn = (wave & 1) * 64;
    int lr = lane & 15, lk = lane >> 4;
    int sr = tid >> 3, sc = (tid & 7) * 8;

    f32x4 acc[4][4];
    #pragma unroll
    for (int i = 0; i < 4; ++i)
        #pragma unroll
        for (int j = 0; j < 4; ++j) acc[i][j] = (f32x4){0.f, 0.f, 0.f, 0.f};

    const ushort* Ap = Ag + (size_t)(bm + sr) * KD + sc;
    const ushort* Bp = Bg + (size_t)(bn + sr) * KD + sc;

    uint4 ra[4], rb[4];
    #pragma unroll
    for (int e = 0; e < 4; ++e) {
        ra[e] = *(const uint4*)(Ap + (size_t)e * 32 * KD);
        rb[e] = *(const uint4*)(Bp + (size_t)e * 32 * KD);
    }

    for (int k0 = 0; k0 < KD; k0 += 64) {
        __syncthreads();
        #pragma unroll
        for (int e = 0; e < 4; ++e) {
            *(uint4*)&As[sr + e * 32][sc] = ra[e];
            *(uint4*)&Bs[sr + e * 32][sc] = rb[e];
        }
        __syncthreads();
        if (k0 + 64 < KD) {
            #pragma unroll
            for (int e = 0; e < 4; ++e) {
                ra[e] = *(const uint4*)(Ap + (size_t)e * 32 * KD + k0 + 64);
                rb[e] = *(const uint4*)(Bp + (size_t)e * 32 * KD + k0 + 64);
            }
        }
        #pragma unroll
        for (int ks = 0; ks < 2; ++ks) {
            short8 af[4], bfr[4];
            #pragma unroll
            for (int i = 0; i < 4; ++i)
                af[i] = *(const short8*)&As[wm + i * 16 + lr][ks * 32 + lk * 8];
            #pragma unroll
            for (int j = 0; j < 4; ++j)
                bfr[j] = *(const short8*)&Bs[wn + j * 16 + lr][ks * 32 + lk * 8];
            #pragma unroll
            for (int i = 0; i < 4; ++i)
                #pragma unroll
                for (int j = 0; j < 4; ++j)
                    acc[i][j] = __builtin_amdgcn_mfma_f32_16x16x32_bf16(
                        af[i], bfr[j], acc[i][j], 0, 0, 0);
        }
    }

    #pragma unroll
    for (int i = 0; i < 4; ++i) {
        #pragma unroll
        for (int j = 0; j < 4; ++j) {
            int col = bn + wn + j * 16 + lr;
            float bv = bias[col];
            #pragma unroll
            for (int r = 0; r < 4; ++r) {
                int row = bm + wm + i * 16 + lk * 4 + r;
                Cm[(size_t)row * NN + col] = acc[i][j][r] + bv;
            }
        }
    }
}

// ---------------------------------------------------------------------------
// Prep kernels: dtype conversion and transposes (LDS-staged, pad 65).
// ---------------------------------------------------------------------------
__global__ __launch_bounds__(256) void xbf_kernel(
    const float* __restrict__ x, ushort* __restrict__ xbf)
{
    int i = blockIdx.x * 256 + threadIdx.x;       // 524288/4 = 131072 threads
    float4 v = *(const float4*)&x[(size_t)i * 4];
    union { ushort u[4]; uint2 p; } o;
    o.u[0] = f2bf(v.x); o.u[1] = f2bf(v.y);
    o.u[2] = f2bf(v.z); o.u[3] = f2bf(v.w);
    *(uint2*)&xbf[(size_t)i * 4] = o.p;
}

// W1[h,d,c] fp32 -> w1t[h*64+c][d] bf16. grid = 64 heads * 4 d-chunks
__global__ __launch_bounds__(256) void w1t_kernel(
    const float* __restrict__ W1, ushort* __restrict__ w1t)
{
    int blk = blockIdx.x; int h = blk >> 2, d0 = (blk & 3) * 64;
    __shared__ float lw[64][65];
    int tid = threadIdx.x;
    for (int e = 0; e < 16; ++e) {
        int idx = e * 256 + tid; int dr = idx >> 6, c = idx & 63;
        lw[dr][c] = W1[((size_t)h * D + d0 + dr) * C1 + c];
    }
    __syncthreads();
    for (int e = 0; e < 16; ++e) {
        int idx = e * 256 + tid; int c = idx >> 6, dr = idx & 63;
        w1t[((size_t)(h * 64 + c)) * D + d0 + dr] = f2bf(lw[dr][c]);
    }
}

// W2[h,k,c] fp32 -> w2t[h*20+c][k] bf16. grid = 64 heads * 32 k-chunks(128)
__global__ __launch_bounds__(256) void w2t_kernel(
    const float* __restrict__ W2, ushort* __restrict__ w2t)
{
    int blk = blockIdx.x; int h = blk >> 5, kb = blk & 31; int k0 = kb * 128;
    __shared__ float lw[128][21];
    int tid = threadIdx.x;
    const float* src = W2 + ((size_t)h * K2 + k0) * C2;
    for (int e = 0; e < 10; ++e) {
        int idx = e * 256 + tid; int k = idx / 20, c = idx - k * 20;
        lw[k][c] = src[idx];
    }
    __syncthreads();
    for (int e = 0; e < 10; ++e) {
        int idx = e * 256 + tid; int c = idx >> 7, k = idx & 127;
        w2t[((size_t)(h * 20 + c)) * K2 + k0 + k] = f2bf(lw[k][c]);
    }
}

// slw[k=1280][d=256] fp32 -> slwt[d][k] bf16. grid = 20 k-chunks * 4 d-chunks
__global__ __launch_bounds__(256) void slwt_kernel(
    const float* __restrict__ slw, ushort* __restrict__ slwt)
{
    int blk = blockIdx.x; int kb = blk >> 2, d0 = (blk & 3) * 64; int k0 = kb * 64;
    __shared__ float lw[64][65];
    int tid = threadIdx.x;
    for (int e = 0; e < 16; ++e) {
        int idx = e * 256 + tid; int kr = idx >> 6, dc = idx & 63;
        lw[kr][dc] = slw[((size_t)(k0 + kr)) * D + d0 + dc];
    }
    __syncthreads();
    for (int e = 0; e < 16; ++e) {
        int idx = e * 256 + tid; int dr = idx >> 6, kc = idx & 63;
        slwt[((size_t)(d0 + dr)) * F2 + k0 + kc] = f2bf(lw[kc][dr]);
    }
}

// ---------------------------------------------------------------------------
// attention-1: reads wh1m[b*T+t][h*64+c] fp32; computes scores in-kernel;
// writes c1 bf16 [b*T+t][h*64+c].
// ---------------------------------------------------------------------------
__global__ __launch_bounds__(256) void attn1_kernel(
    const float* __restrict__ wh1m, const float* __restrict__ a1s,
    const float* __restrict__ a1d, const float* __restrict__ a1b,
    ushort* __restrict__ c1)
{
    int blk = blockIdx.x; int b = blk >> 6, h = blk & 63;
    __shared__ float whs[128][65];
    __shared__ alignas(16) float pT[4][128][4];
    __shared__ float ss[128], ddv[128];
    int tid = threadIdx.x; int w = tid >> 6, lane = tid & 63;

    for (int e = 0; e < 32; ++e) {
        int idx = e * 256 + tid; int t = idx >> 6, c = idx & 63;
        whs[t][c] = wh1m[((size_t)(b * T + t)) * K2 + h * C1 + c];
    }
    __syncthreads();
    if (tid < 128) {
        float s = a1b[h], dv = 0.f;
        #pragma unroll
        for (int c = 0; c < 64; ++c) {
            float v = whs[tid][c];
            s  = fmaf(v, a1s[h * C1 + c], s);
            dv = fmaf(v, a1d[h * C1 + c], dv);
        }
        ss[tid] = s; ddv[tid] = dv;
    }
    __syncthreads();

    float dj0 = ddv[lane], dj1 = ddv[lane + 64];
    for (int q = 0; q < 8; ++q) {
        for (int r = 0; r < 4; ++r) {
            int i = w * 32 + q * 4 + r;
            float si = ss[i];
            float e0 = si + dj0; e0 = e0 >= 0.f ? e0 : ALPHA * e0;
            float e1 = si + dj1; e1 = e1 >= 0.f ? e1 : ALPHA * e1;
            float m = fmaxf(e0, e1);
            for (int msk = 1; msk < 64; msk <<= 1) m = fmaxf(m, __shfl_xor(m, msk));
            float p0 = __expf(e0 - m), p1 = __expf(e1 - m);
            float sum = p0 + p1;
            for (int msk = 1; msk < 64; msk <<= 1) sum += __shfl_xor(sum, msk);
            float inv = 1.0f / sum;
            pT[w][lane][r] = p0 * inv; pT[w][lane + 64][r] = p1 * inv;
        }
        float a0 = 0, a1 = 0, a2 = 0, a3 = 0;
        for (int j = 0; j < 128; ++j) {
            float4 pv = *(const float4*)&pT[w][j][0];
            float wj = whs[j][lane];
            a0 = fmaf(pv.x, wj, a0); a1 = fmaf(pv.y, wj, a1);
            a2 = fmaf(pv.z, wj, a2); a3 = fmaf(pv.w, wj, a3);
        }
        int i0 = w * 32 + q * 4;
        float vals[4] = {a0, a1, a2, a3};
        #pragma unroll
        for (int r = 0; r < 4; ++r) {
            float v = vals[r]; v = v > 0.f ? v : 0.f;
            v = 1.0f / (1.0f + __expf(-v));
            c1[((size_t)(b * T + i0 + r)) * K2 + h * C1 + lane] = f2bf(v);
        }
    }
}

// ---------------------------------------------------------------------------
// attention-2: reads wh2m[b*T+t][h*20+c] fp32; writes c2 bf16 same layout.
// ---------------------------------------------------------------------------
__global__ __launch_bounds__(256) void attn2_kernel(
    const float* __restrict__ wh2m, const float* __restrict__ a2s,
    const float* __restrict__ a2d, const float* __restrict__ a2b,
    ushort* __restrict__ c2)
{
    int blk = blockIdx.x; int b = blk >> 6, h = blk & 63;
    __shared__ float whs[128][33];
    __shared__ alignas(16) float pT[4][128][4];
    __shared__ float ss[128], ddv[128];
    int tid = threadIdx.x; int w = tid >> 6, lane = tid & 63;
    const float* src = wh2m + (size_t)b * T * F2 + h * C2;

    for (int e = 0; e < 10; ++e) {
        int idx = e * 256 + tid; int t = idx / 20, c = idx - t * 20;
        whs[t][c] = src[(size_t)t * F2 + c];
    }
    for (int e = 0; e < 7; ++e) {
        int idx = e * 256 + tid;
        if (idx < 1664) { int t = idx / 13, c = 20 + (idx - t * 13); whs[t][c] = 0.f; }
    }
    __syncthreads();
    if (tid < 128) {
        float s = a2b[h], dv = 0.f;
        #pragma unroll
        for (int c = 0; c < 20; ++c) {
            float v = whs[tid][c];
            s  = fmaf(v, a2s[h * C2 + c], s);
            dv = fmaf(v, a2d[h * C2 + c], dv);
        }
        ss[tid] = s; ddv[tid] = dv;
    }
    __syncthreads();

    float dj0 = ddv[lane], dj1 = ddv[lane + 64];
    int cc = lane & 31, jh = lane >> 5;
    for (int q = 0; q < 8; ++q) {
        for (int r = 0; r < 4; ++r) {
            int i = w * 32 + q * 4 + r;
            float si = ss[i];
            float e0 = si + dj0; e0 = e0 >= 0.f ? e0 : ALPHA * e0;
            float e1 = si + dj1; e1 = e1 >= 0.f ? e1 : ALPHA * e1;
            float m = fmaxf(e0, e1);
            for (int msk = 1; msk < 64; msk <<= 1) m = fmaxf(m, __shfl_xor(m, msk));
            float p0 = __expf(e0 - m), p1 = __expf(e1 - m);
            float sum = p0 + p1;
            for (int msk = 1; msk < 64; msk <<= 1) sum += __shfl_xor(sum, msk);
            float inv = 1.0f / sum;
            pT[w][lane][r] = p0 * inv; pT[w][lane + 64][r] = p1 * inv;
        }
        float a0 = 0, a1 = 0, a2 = 0, a3 = 0;
        for (int jj = 0; jj < 64; ++jj) {
            int j = jh * 64 + jj;
            float4 pv = *(const float4*)&pT[w][j][0];
            float wj = whs[j][cc];
            a0 = fmaf(pv.x, wj, a0); a1 = fmaf(pv.y, wj, a1);
            a2 = fmaf(pv.z, wj, a2); a3 = fmaf(pv.w, wj, a3);
        }
        a0 += __shfl_xor(a0, 32); a1 += __shfl_xor(a1, 32);
        a2 += __shfl_xor(a2, 32); a3 += __shfl_xor(a3, 32);
        if (jh == 0 && cc < 20) {
            int i0 = w * 32 + q * 4;
            float vals[4] = {a0, a1, a2, a3};
            #pragma unroll
            for (int r = 0; r < 4; ++r) {
                float v = vals[r]; v = v > 0.f ? v : 0.f;
                v = 1.0f / (1.0f + __expf(-v));
                c2[((size_t)(b * T + i0 + r)) * F2 + h * C2 + cc] = f2bf(v);
            }
        }
    }
}

// ---------------------------------------------------------------------------
// GAR: res[b,o,d] = sum_t c3[b,t,d]*gar_w[t,o] + gar_b[o]
// ---------------------------------------------------------------------------
__global__ __launch_bounds__(256) void gar_kernel(
    const float* __restrict__ c3, const float* __restrict__ garw,
    const float* __restrict__ garb, float* __restrict__ out)
{
    int blk = blockIdx.x; int b = blk >> 5, o = blk & 31;
    int dcol = threadIdx.x;
    float acc = garb[o];
    const float* cp = c3 + (size_t)b * T * D + dcol;
    for (int t = 0; t < T; ++t)
        acc = fmaf(cp[(size_t)t * D], garw[t * OUTW + o], acc);
    out[((size_t)b * OUTW + o) * D + dcol] = acc;
}

// ---------------------------------------------------------------------------
extern "C" void kernel_launch(void* const* d_in, const int* in_sizes, int n_in,
                              void* d_out, int out_size, void* d_ws, size_t ws_size,
                              hipStream_t stream) {
    const float* x    = (const float*)d_in[0];
    const float* W1   = (const float*)d_in[1];
    const float* b1   = (const float*)d_in[2];
    const float* a1s  = (const float*)d_in[3];
    const float* a1d  = (const float*)d_in[4];
    const float* a1b  = (const float*)d_in[5];
    const float* W2   = (const float*)d_in[6];
    const float* b2   = (const float*)d_in[7];
    const float* a2s  = (const float*)d_in[8];
    const float* a2d  = (const float*)d_in[9];
    const float* a2b  = (const float*)d_in[10];
    const float* slw  = (const float*)d_in[11];
    const float* slb  = (const float*)d_in[12];
    const float* garw = (const float*)d_in[13];
    const float* garb = (const float*)d_in[14];

    char* p = (char*)d_ws;
    float*  wh1m = (float*)p;               p += (size_t)2048 * 4096 * 4;  // 33.5 MB
    float*  wh2m = (float*)p;               p += (size_t)2048 * 1280 * 4;  // 10.5 MB
    float*  c3   = (float*)p;               p += (size_t)2048 * 256  * 4;  //  2.1 MB
    ushort* xbf  = (ushort*)p;              p += (size_t)2048 * 256  * 2;  //  1.0 MB
    ushort* w1t  = (ushort*)p;              p += (size_t)4096 * 256  * 2;  //  2.1 MB
    ushort* c1bf = (ushort*)p;              p += (size_t)2048 * 4096 * 2;  // 16.8 MB
    ushort* w2t  = (ushort*)p;              p += (size_t)1280 * 4096 * 2;  // 10.5 MB
    ushort* c2bf = (ushort*)p;              p += (size_t)2048 * 1280 * 2;  //  5.2 MB
    ushort* slwt = (ushort*)p;              p += (size_t)256  * 1280 * 2;  //  0.7 MB

    xbf_kernel <<<512,  256, 0, stream>>>(x, xbf);
    w1t_kernel <<<256,  256, 0, stream>>>(W1, w1t);
    w2t_kernel <<<2048, 256, 0, stream>>>(W2, w2t);
    slwt_kernel<<<80,   256, 0, stream>>>(slw, slwt);

    gemm_bf16_kernel<256, 32><<<512, 256, 0, stream>>>(xbf, w1t, b1, wh1m);
    attn1_kernel<<<B * H, 256, 0, stream>>>(wh1m, a1s, a1d, a1b, c1bf);
    gemm_bf16_kernel<4096, 10><<<160, 256, 0, stream>>>(c1bf, w2t, b2, wh2m);
    attn2_kernel<<<B * H, 256, 0, stream>>>(wh2m, a2s, a2d, a2b, c2bf);
    gemm_bf16_kernel<1280, 2><<<32, 256, 0, stream>>>(c2bf, slwt, slb, c3);
    gar_kernel<<<B * OUTW, 256, 0, stream>>>(c3, garw, garb, (float*)d_out);
}